// Round 2
// baseline (520.697 us; speedup 1.0000x reference)
//
#include <hip/hip_runtime.h>
#include <math.h>

#define BATCH_ 65536
#define NN 512
#define KK 48
#define OFF_HHRE (2*BATCH_*KK)            // 6291456
#define OFF_HHIM (OFF_HHRE + BATCH_*NN)   // 39845888

typedef float f32x4 __attribute__((ext_vector_type(4)));
typedef int   i32x4 __attribute__((ext_vector_type(4)));

// ---- ws layout (byte offsets) ----
#define WS_PB    0u         // 2*32*2*512 bf16 = 262144 B
#define WS_PA    262144u    // 2*16*3*512 bf16 =  98304 B (ends 360448)
#define WS_SIGP  393216u    // 256 f32
#define WS_SIGMA 394240u    // 1 f32
#define WS_BPART 395264u    // 8192*2 f32 = 64 KB (ends 460800)
#define WS_BVAL  460800u    // 2 f32

__device__ __forceinline__ unsigned short f2bf(float x) {
  unsigned u = __builtin_bit_cast(unsigned, x);
  unsigned r = (u + 0x7fffu + ((u >> 16) & 1u)) >> 16;
  return (unsigned short)r;
}
__device__ __forceinline__ int pack2bf(float a, float b) {
  return (int)f2bf(a) | ((int)f2bf(b) << 16);
}
__device__ __forceinline__ i32x4 pack8bf(f32x4 a, f32x4 b) {
  i32x4 r;
  r.x = pack2bf(a.x, a.y); r.y = pack2bf(a.z, a.w);
  r.z = pack2bf(b.x, b.y); r.w = pack2bf(b.z, b.w);
  return r;
}
__device__ __forceinline__ float waveRed(float v) {
#pragma unroll
  for (int o = 32; o > 0; o >>= 1) v += __shfl_down(v, o);
  return v;
}

// inline-asm MFMA; s_nop 1 covers VALU-write -> MFMA-read SrcA/B hazard.
#define MFMA16(acc, a, b) \
  asm volatile("s_nop 1\n\tv_mfma_f32_16x16x32_bf16 %0, %1, %2, %0" \
               : "+v"(acc) : "v"(a), "v"(b))

// ---------------- pack B/A into fragment-ordered bf16 ----------------
// PB[mat][nt:32][ks:2][lane:64][j:8] = B_mat[nt*16 + (l&15)][ks*32+(l>>4)*8+j], 0 pad k>=48
// PA[mat][ks:16][ct:3][lane:64][j:8] = A_mat[ks*32+(l>>4)*8+j][ct*16 + (l&15)]
__global__ void lamp_pack(const float* __restrict__ Bre, const float* __restrict__ Bim,
                          const float* __restrict__ Are, const float* __restrict__ Aim,
                          unsigned short* __restrict__ pb, unsigned short* __restrict__ pa)
{
  int i = blockIdx.x * 256 + threadIdx.x;
  const int NPB = 2*32*2*512;   // 65536
  const int NPA = 2*16*3*512;   // 49152
  if (i < NPB) {
    int j = i & 7, l = (i >> 3) & 63, ks = (i >> 9) & 1, nt = (i >> 10) & 31, mat = i >> 15;
    int k = ks*32 + (l >> 4)*8 + j;
    int n = nt*16 + (l & 15);
    float v = 0.f;
    if (k < KK) v = mat ? Bim[n*KK + k] : Bre[n*KK + k];
    pb[i] = f2bf(v);
  } else if (i < NPB + NPA) {
    int i2 = i - NPB;
    int j = i2 & 7, l = (i2 >> 3) & 63;
    int rem = i2 >> 9;          // (mat*16+ks)*3 + ct
    int ct = rem % 3; rem /= 3;
    int ks = rem & 15; int mat = rem >> 4;
    int k = ks*32 + (l >> 4)*8 + j;
    int c = ct*16 + (l & 15);
    float v = mat ? Aim[k*KK + c] : Are[k*KK + c];
    pa[i2] = f2bf(v);
  }
}

// ---------------- sigma ----------------
__global__ void lamp_sig(const float* __restrict__ zr, const float* __restrict__ zi,
                         float* __restrict__ part)
{
  const int n4 = BATCH_*KK/4;
  const f32x4* a = (const f32x4*)zr; const f32x4* b = (const f32x4*)zi;
  float s = 0.f;
  for (int i = blockIdx.x*blockDim.x + threadIdx.x; i < n4; i += gridDim.x*blockDim.x) {
    f32x4 x = a[i]; s += x.x*x.x + x.y*x.y + x.z*x.z + x.w*x.w;
    f32x4 y = b[i]; s += y.x*y.x + y.y*y.y + y.z*y.z + y.w*y.w;
  }
  __shared__ float red[4];
  s = waveRed(s);
  int wave = threadIdx.x >> 6, lane = threadIdx.x & 63;
  if (lane == 0) red[wave] = s;
  __syncthreads();
  if (threadIdx.x == 0) part[blockIdx.x] = red[0]+red[1]+red[2]+red[3];
}

__global__ void lamp_sigfin(const float* __restrict__ part, float* __restrict__ sig)
{
  float s = part[threadIdx.x];   // 256 partials
  __shared__ float red[4];
  s = waveRed(s);
  int wave = threadIdx.x >> 6, lane = threadIdx.x & 63;
  if (lane == 0) red[wave] = s;
  __syncthreads();
  if (threadIdx.x == 0) sig[0] = sqrtf(red[0]+red[1]+red[2]+red[3]) / sqrtf((float)KK);
}

// ---------------- main fused kernel ----------------
// 2048 blocks x 256 thr. Wave w: row-tile t = w>>1 (16 rows), col-half ch = w&1
// (16 of the 32 col-tiles). 8192 waves total -> 32 waves/CU. GEMM2 partial
// accumulators combined via atomicAdd into pre-zeroed z-slots of d_out
// (exactly 2 commutative contributions per address -> deterministic).
__global__ __launch_bounds__(256, 8) void lamp_main(
    const float* __restrict__ zre, const float* __restrict__ zim,
    const float* __restrict__ Hre, const float* __restrict__ Him,
    const unsigned short* __restrict__ pb, const unsigned short* __restrict__ pa,
    const float* __restrict__ sigp, const float* __restrict__ theta,
    float* __restrict__ out, float* __restrict__ bpart)
{
  __shared__ float tbuf[4][2][16*36];   // per-wave transpose buffer, stride 36 (bank-clean)

  const int tid = threadIdx.x;
  const int wave = tid >> 6, lane = tid & 63;
  const int t = wave >> 1, ch = wave & 1;
  const int l15 = lane & 15, lg = lane >> 4;
  const int rbase = blockIdx.x * 32 + t * 16;

  const float t0 = theta[0], t1 = theta[1], t2 = theta[2];
  const float sigma = sigp[0];
  const float s2 = (t0 * sigma) * (t0 * sigma);
  const float inv_s2 = 1.0f / s2;
  const float nhalf_inv_s2 = -0.5f * inv_s2;

  // z fragments (A operand of GEMM1), K padded 48->64
  i32x4 zr[2], zi[2], nzi[2];
  {
    const int myrow = rbase + l15;
    const float* pr = zre + (size_t)myrow * KK;
    const float* pi = zim + (size_t)myrow * KK;
#pragma unroll
    for (int ks = 0; ks < 2; ++ks) {
      const int k0 = ks*32 + lg*8;
      f32x4 a0 = {0,0,0,0}, a1 = {0,0,0,0}, b0 = {0,0,0,0}, b1 = {0,0,0,0};
      if (k0 < KK) {
        a0 = *(const f32x4*)(pr + k0); a1 = *(const f32x4*)(pr + k0 + 4);
        b0 = *(const f32x4*)(pi + k0); b1 = *(const f32x4*)(pi + k0 + 4);
      }
      zr[ks]  = pack8bf(a0, a1);
      zi[ks]  = pack8bf(b0, b1);
      nzi[ks] = zi[ks] ^ 0x80008000;
    }
  }

  const i32x4* pb4 = (const i32x4*)pb;
  const i32x4* pa4 = (const i32x4*)pa;

  f32x4 ah[3][2];
#pragma unroll
  for (int c = 0; c < 3; ++c) {
    ah[c][0] = (f32x4){0,0,0,0};
    ah[c][1] = (f32x4){0,0,0,0};
  }

  float dsr = 0.f, dsi = 0.f;
  float* trow0 = &tbuf[wave][0][0];
  float* trow1 = &tbuf[wave][1][0];

  for (int i = 0; i < 16; ++i) {
    const int n0 = ch * 16 + i;
    // ---- GEMM1: Z tile (16 rows x 16 cols), K=64 ----
    i32x4 br0 = pb4[(n0*2 + 0)*64 + lane];
    i32x4 br1 = pb4[(n0*2 + 1)*64 + lane];
    i32x4 bi0 = pb4[((32 + n0)*2 + 0)*64 + lane];
    i32x4 bi1 = pb4[((32 + n0)*2 + 1)*64 + lane];
    f32x4 accR = (f32x4){0,0,0,0}, accI = (f32x4){0,0,0,0};
    MFMA16(accR, zr[0],  br0);  MFMA16(accR, zr[1],  br1);
    MFMA16(accR, nzi[0], bi0);  MFMA16(accR, nzi[1], bi1);
    MFMA16(accI, zr[0],  bi0);  MFMA16(accI, zr[1],  bi1);
    MFMA16(accI, zi[0],  br0);  MFMA16(accI, zi[1],  br1);
    asm volatile("s_nop 7\n\ts_nop 7" : "+v"(accR), "+v"(accI));  // MFMA->VALU hazard fence

    // ---- fused elementwise: R = H + Z, shrink, deriv, store Hh ----
    const int nb = n0*16 + l15;
    const int row0 = rbase + lg*4;
    const float* hr = Hre + (size_t)row0 * NN + nb;
    const float* hi = Him + (size_t)row0 * NN + nb;
    float* oR = out + OFF_HHRE + (size_t)row0 * NN + nb;
    float* oI = out + OFF_HHIM + (size_t)row0 * NN + nb;
    const int tcol = (i & 1) * 16 + l15;
#pragma unroll
    for (int rg = 0; rg < 4; ++rg) {
      float re = accR[rg] + hr[(size_t)rg * NN];
      float im = accI[rg] + hi[(size_t)rg * NN];
      float er = __expf(re*re*nhalf_inv_s2);
      float ei = __expf(im*im*nhalf_inv_s2);
      float hhr = t1*re + t2*re*er;
      float hhi = t1*im + t2*im*ei;
      dsr += t1 + t2*er*(1.f - re*re*inv_s2);
      dsi += t1 + t2*ei*(1.f - im*im*inv_s2);
      oR[(size_t)rg * NN] = hhr;
      oI[(size_t)rg * NN] = hhi;
      trow0[(lg*4 + rg)*36 + tcol] = hhr;   // stage for transpose
      trow1[(lg*4 + rg)*36 + tcol] = hhi;
    }

    // ---- GEMM2 partial: consume 32-col chunk as K-slice (same-wave LDS, in-order) ----
    if (i & 1) {
      const int ks = ch * 8 + (i >> 1);
      f32x4 w0 = *(const f32x4*)&trow0[l15*36 + lg*8];
      f32x4 w1 = *(const f32x4*)&trow0[l15*36 + lg*8 + 4];
      f32x4 v0 = *(const f32x4*)&trow1[l15*36 + lg*8];
      f32x4 v1 = *(const f32x4*)&trow1[l15*36 + lg*8 + 4];
      i32x4 ar  = pack8bf(w0, w1);
      i32x4 ai  = pack8bf(v0, v1);
      i32x4 nai = ai ^ 0x80008000;
#pragma unroll
      for (int ct = 0; ct < 3; ++ct) {
        i32x4 par = pa4[(ks*3 + ct)*64 + lane];
        i32x4 pai = pa4[((16 + ks)*3 + ct)*64 + lane];
        MFMA16(ah[ct][0], ar,  par);
        MFMA16(ah[ct][0], nai, pai);
        MFMA16(ah[ct][1], ar,  pai);
        MFMA16(ah[ct][1], ai,  par);
      }
    }
  }

  asm volatile("s_nop 7\n\ts_nop 7"
               : "+v"(ah[0][0]), "+v"(ah[0][1]), "+v"(ah[1][0]),
                 "+v"(ah[1][1]), "+v"(ah[2][0]), "+v"(ah[2][1]));

  // combine the two col-half partials of h via atomics into pre-zeroed out z-slots
#pragma unroll
  for (int ct = 0; ct < 3; ++ct) {
#pragma unroll
    for (int rg = 0; rg < 4; ++rg) {
      const int row = rbase + lg*4 + rg;
      atomicAdd(&out[(size_t)row*KK + ct*16 + l15], ah[ct][0][rg]);
      atomicAdd(&out[(size_t)(BATCH_*KK) + (size_t)row*KK + ct*16 + l15], ah[ct][1][rg]);
    }
  }

  // per-wave deriv partials (no block reduction needed)
  float rr = waveRed(dsr), ri = waveRed(dsi);
  if (lane == 0) {
    const int w = blockIdx.x * 4 + wave;
    bpart[2*w]     = rr;
    bpart[2*w + 1] = ri;
  }
}

// ---------------- b reduce (8192 wave-partials) ----------------
__global__ void lamp_bred(const float* __restrict__ bpart, float* __restrict__ bval)
{
  float sr = 0.f, si = 0.f;
  for (int m = threadIdx.x; m < 8192; m += 256) { sr += bpart[2*m]; si += bpart[2*m + 1]; }
  __shared__ float red[8];
  sr = waveRed(sr); si = waveRed(si);
  int wave = threadIdx.x >> 6, lane = threadIdx.x & 63;
  if (lane == 0) { red[wave] = sr; red[4 + wave] = si; }
  __syncthreads();
  if (threadIdx.x == 0) {
    bval[0] = (red[0]+red[1]+red[2]+red[3]) / (float)KK;
    bval[1] = (red[4]+red[5]+red[6]+red[7]) / (float)KK;
  }
}

// ---------------- z_new (in-place over accumulated h) ----------------
__global__ void lamp_znew(const float* __restrict__ ur, const float* __restrict__ ui,
                          const float* __restrict__ zr, const float* __restrict__ zi,
                          const float* __restrict__ bval, float* __restrict__ out)
{
  const float br = bval[0], bi = bval[1];
  const int n4 = BATCH_*KK/4;
  const f32x4* u4r = (const f32x4*)ur; const f32x4* u4i = (const f32x4*)ui;
  const f32x4* z4r = (const f32x4*)zr; const f32x4* z4i = (const f32x4*)zi;
  f32x4* o4r = (f32x4*)out;
  f32x4* o4i = (f32x4*)(out + BATCH_*KK);
  for (int i = blockIdx.x*blockDim.x + threadIdx.x; i < n4; i += gridDim.x*blockDim.x) {
    f32x4 h = o4r[i];
    o4r[i] = u4r[i] - h + br * z4r[i];
    f32x4 h2 = o4i[i];
    o4i[i] = u4i[i] - h2 + bi * z4i[i];
  }
}

extern "C" void kernel_launch(void* const* d_in, const int* in_sizes, int n_in,
                              void* d_out, int out_size, void* d_ws, size_t ws_size,
                              hipStream_t stream)
{
  const float* ur  = (const float*)d_in[0];
  const float* ui  = (const float*)d_in[1];
  const float* zr  = (const float*)d_in[2];
  const float* zi  = (const float*)d_in[3];
  const float* Hr  = (const float*)d_in[4];
  const float* Hi  = (const float*)d_in[5];
  const float* Bre = (const float*)d_in[6];
  const float* Bim = (const float*)d_in[7];
  const float* Are = (const float*)d_in[8];
  const float* Aim = (const float*)d_in[9];
  const float* th  = (const float*)d_in[10];
  float* out = (float*)d_out;
  char* ws = (char*)d_ws;
  unsigned short* pb  = (unsigned short*)(ws + WS_PB);
  unsigned short* pa  = (unsigned short*)(ws + WS_PA);
  float* sigp  = (float*)(ws + WS_SIGP);
  float* sigv  = (float*)(ws + WS_SIGMA);
  float* bpart = (float*)(ws + WS_BPART);
  float* bval  = (float*)(ws + WS_BVAL);

  // zero the z-slots of out: they receive h via atomicAdd (2 contributions each)
  hipMemsetAsync(out, 0, (size_t)(2*BATCH_*KK) * sizeof(float), stream);

  hipLaunchKernelGGL(lamp_pack,   dim3(448),  dim3(256), 0, stream, Bre, Bim, Are, Aim, pb, pa);
  hipLaunchKernelGGL(lamp_sig,    dim3(256),  dim3(256), 0, stream, zr, zi, sigp);
  hipLaunchKernelGGL(lamp_sigfin, dim3(1),    dim3(256), 0, stream, sigp, sigv);
  hipLaunchKernelGGL(lamp_main,   dim3(2048), dim3(256), 0, stream,
                     zr, zi, Hr, Hi, pb, pa, sigv, th, out, bpart);
  hipLaunchKernelGGL(lamp_bred,   dim3(1),    dim3(256), 0, stream, bpart, bval);
  hipLaunchKernelGGL(lamp_znew,   dim3(1024), dim3(256), 0, stream, ur, ui, zr, zi, bval, out);
}

// Round 3
// 240.133 us; speedup vs baseline: 2.1684x; 2.1684x over previous
//
#include <hip/hip_runtime.h>
#include <math.h>

#define BATCH_ 65536
#define NN 512
#define KK 48
#define OFF_HHRE (2*BATCH_*KK)            // 6291456
#define OFF_HHIM (OFF_HHRE + BATCH_*NN)   // 39845888

typedef float f32x4 __attribute__((ext_vector_type(4)));
typedef int   i32x4 __attribute__((ext_vector_type(4)));

// ---- ws layout (byte offsets) ----
#define WS_PB    0u         // 2*32*2*512 bf16 = 262144 B
#define WS_PA    262144u    // 2*16*3*512 bf16 =  98304 B (ends 360448)
#define WS_SIGP  393216u    // 256 f32
#define WS_SIGMA 394240u    // 1 f32
#define WS_BPART 395264u    // 8192*2 f32 = 64 KB (ends 460800)
#define WS_BVAL  460800u    // 2 f32

__device__ __forceinline__ unsigned short f2bf(float x) {
  unsigned u = __builtin_bit_cast(unsigned, x);
  unsigned r = (u + 0x7fffu + ((u >> 16) & 1u)) >> 16;
  return (unsigned short)r;
}
__device__ __forceinline__ int pack2bf(float a, float b) {
  return (int)f2bf(a) | ((int)f2bf(b) << 16);
}
__device__ __forceinline__ i32x4 pack8bf(f32x4 a, f32x4 b) {
  i32x4 r;
  r.x = pack2bf(a.x, a.y); r.y = pack2bf(a.z, a.w);
  r.z = pack2bf(b.x, b.y); r.w = pack2bf(b.z, b.w);
  return r;
}
__device__ __forceinline__ float waveRed(float v) {
#pragma unroll
  for (int o = 32; o > 0; o >>= 1) v += __shfl_down(v, o);
  return v;
}

// inline-asm MFMA; s_nop 1 covers VALU-write -> MFMA-read SrcA/B hazard.
#define MFMA16(acc, a, b) \
  asm volatile("s_nop 1\n\tv_mfma_f32_16x16x32_bf16 %0, %1, %2, %0" \
               : "+v"(acc) : "v"(a), "v"(b))

// ---------------- pack B/A into fragment-ordered bf16 ----------------
// PB[mat][nt:32][ks:2][lane:64][j:8] = B_mat[nt*16 + (l&15)][ks*32+(l>>4)*8+j], 0 pad k>=48
// PA[mat][ks:16][ct:3][lane:64][j:8] = A_mat[ks*32+(l>>4)*8+j][ct*16 + (l&15)]
__global__ void lamp_pack(const float* __restrict__ Bre, const float* __restrict__ Bim,
                          const float* __restrict__ Are, const float* __restrict__ Aim,
                          unsigned short* __restrict__ pb, unsigned short* __restrict__ pa)
{
  int i = blockIdx.x * 256 + threadIdx.x;
  const int NPB = 2*32*2*512;   // 65536
  const int NPA = 2*16*3*512;   // 49152
  if (i < NPB) {
    int j = i & 7, l = (i >> 3) & 63, ks = (i >> 9) & 1, nt = (i >> 10) & 31, mat = i >> 15;
    int k = ks*32 + (l >> 4)*8 + j;
    int n = nt*16 + (l & 15);
    float v = 0.f;
    if (k < KK) v = mat ? Bim[n*KK + k] : Bre[n*KK + k];
    pb[i] = f2bf(v);
  } else if (i < NPB + NPA) {
    int i2 = i - NPB;
    int j = i2 & 7, l = (i2 >> 3) & 63;
    int rem = i2 >> 9;          // (mat*16+ks)*3 + ct
    int ct = rem % 3; rem /= 3;
    int ks = rem & 15; int mat = rem >> 4;
    int k = ks*32 + (l >> 4)*8 + j;
    int c = ct*16 + (l & 15);
    float v = mat ? Aim[k*KK + c] : Are[k*KK + c];
    pa[i2] = f2bf(v);
  }
}

// ---------------- sigma ----------------
__global__ void lamp_sig(const float* __restrict__ zr, const float* __restrict__ zi,
                         float* __restrict__ part)
{
  const int n4 = BATCH_*KK/4;
  const f32x4* a = (const f32x4*)zr; const f32x4* b = (const f32x4*)zi;
  float s = 0.f;
  for (int i = blockIdx.x*blockDim.x + threadIdx.x; i < n4; i += gridDim.x*blockDim.x) {
    f32x4 x = a[i]; s += x.x*x.x + x.y*x.y + x.z*x.z + x.w*x.w;
    f32x4 y = b[i]; s += y.x*y.x + y.y*y.y + y.z*y.z + y.w*y.w;
  }
  __shared__ float red[4];
  s = waveRed(s);
  int wave = threadIdx.x >> 6, lane = threadIdx.x & 63;
  if (lane == 0) red[wave] = s;
  __syncthreads();
  if (threadIdx.x == 0) part[blockIdx.x] = red[0]+red[1]+red[2]+red[3];
}

__global__ void lamp_sigfin(const float* __restrict__ part, float* __restrict__ sig)
{
  float s = part[threadIdx.x];   // 256 partials
  __shared__ float red[4];
  s = waveRed(s);
  int wave = threadIdx.x >> 6, lane = threadIdx.x & 63;
  if (lane == 0) red[wave] = s;
  __syncthreads();
  if (threadIdx.x == 0) sig[0] = sqrtf(red[0]+red[1]+red[2]+red[3]) / sqrtf((float)KK);
}

// ---------------- main fused kernel ----------------
// 2048 blocks x 256 thr. Wave w: row-tile t = w>>1 (16 rows), col-half ch = w&1
// (16 of the 32 col-tiles). 8192 waves total -> up to 32 waves/CU. GEMM2
// partial accumulators combined via atomicAdd into pre-zeroed z-slots of
// d_out (exactly 2 commutative contributions per address -> deterministic).
// launch_bounds min-waves kept at 4: forcing 8 made the allocator spill
// (R2: VGPR 32, +1 GB scratch traffic). 60 VGPR <= 64 still lets HW run
// 8 blocks/CU.
__global__ __launch_bounds__(256, 4) void lamp_main(
    const float* __restrict__ zre, const float* __restrict__ zim,
    const float* __restrict__ Hre, const float* __restrict__ Him,
    const unsigned short* __restrict__ pb, const unsigned short* __restrict__ pa,
    const float* __restrict__ sigp, const float* __restrict__ theta,
    float* __restrict__ out, float* __restrict__ bpart)
{
  __shared__ float tbuf[4][2][16*36];   // per-wave transpose buffer, stride 36 (bank-clean)

  const int tid = threadIdx.x;
  const int wave = tid >> 6, lane = tid & 63;
  const int t = wave >> 1, ch = wave & 1;
  const int l15 = lane & 15, lg = lane >> 4;
  const int rbase = blockIdx.x * 32 + t * 16;

  const float t0 = theta[0], t1 = theta[1], t2 = theta[2];
  const float sigma = sigp[0];
  const float s2 = (t0 * sigma) * (t0 * sigma);
  const float inv_s2 = 1.0f / s2;
  const float nhalf_inv_s2 = -0.5f * inv_s2;

  // z fragments (A operand of GEMM1), K padded 48->64
  i32x4 zr[2], zi[2], nzi[2];
  {
    const int myrow = rbase + l15;
    const float* pr = zre + (size_t)myrow * KK;
    const float* pi = zim + (size_t)myrow * KK;
#pragma unroll
    for (int ks = 0; ks < 2; ++ks) {
      const int k0 = ks*32 + lg*8;
      f32x4 a0 = {0,0,0,0}, a1 = {0,0,0,0}, b0 = {0,0,0,0}, b1 = {0,0,0,0};
      if (k0 < KK) {
        a0 = *(const f32x4*)(pr + k0); a1 = *(const f32x4*)(pr + k0 + 4);
        b0 = *(const f32x4*)(pi + k0); b1 = *(const f32x4*)(pi + k0 + 4);
      }
      zr[ks]  = pack8bf(a0, a1);
      zi[ks]  = pack8bf(b0, b1);
      nzi[ks] = zi[ks] ^ 0x80008000;
    }
  }

  const i32x4* pb4 = (const i32x4*)pb;
  const i32x4* pa4 = (const i32x4*)pa;

  f32x4 ah[3][2];
#pragma unroll
  for (int c = 0; c < 3; ++c) {
    ah[c][0] = (f32x4){0,0,0,0};
    ah[c][1] = (f32x4){0,0,0,0};
  }

  float dsr = 0.f, dsi = 0.f;
  float* trow0 = &tbuf[wave][0][0];
  float* trow1 = &tbuf[wave][1][0];

  for (int i = 0; i < 16; ++i) {
    const int n0 = ch * 16 + i;
    // ---- GEMM1: Z tile (16 rows x 16 cols), K=64 ----
    i32x4 br0 = pb4[(n0*2 + 0)*64 + lane];
    i32x4 br1 = pb4[(n0*2 + 1)*64 + lane];
    i32x4 bi0 = pb4[((32 + n0)*2 + 0)*64 + lane];
    i32x4 bi1 = pb4[((32 + n0)*2 + 1)*64 + lane];
    f32x4 accR = (f32x4){0,0,0,0}, accI = (f32x4){0,0,0,0};
    MFMA16(accR, zr[0],  br0);  MFMA16(accR, zr[1],  br1);
    MFMA16(accR, nzi[0], bi0);  MFMA16(accR, nzi[1], bi1);
    MFMA16(accI, zr[0],  bi0);  MFMA16(accI, zr[1],  bi1);
    MFMA16(accI, zi[0],  br0);  MFMA16(accI, zi[1],  br1);
    asm volatile("s_nop 7\n\ts_nop 7" : "+v"(accR), "+v"(accI));  // MFMA->VALU hazard fence

    // ---- fused elementwise: R = H + Z, shrink, deriv, store Hh ----
    const int nb = n0*16 + l15;
    const int row0 = rbase + lg*4;
    const float* hr = Hre + (size_t)row0 * NN + nb;
    const float* hi = Him + (size_t)row0 * NN + nb;
    float* oR = out + OFF_HHRE + (size_t)row0 * NN + nb;
    float* oI = out + OFF_HHIM + (size_t)row0 * NN + nb;
    const int tcol = (i & 1) * 16 + l15;
#pragma unroll
    for (int rg = 0; rg < 4; ++rg) {
      float re = accR[rg] + hr[(size_t)rg * NN];
      float im = accI[rg] + hi[(size_t)rg * NN];
      float er = __expf(re*re*nhalf_inv_s2);
      float ei = __expf(im*im*nhalf_inv_s2);
      float hhr = t1*re + t2*re*er;
      float hhi = t1*im + t2*im*ei;
      dsr += t1 + t2*er*(1.f - re*re*inv_s2);
      dsi += t1 + t2*ei*(1.f - im*im*inv_s2);
      oR[(size_t)rg * NN] = hhr;
      oI[(size_t)rg * NN] = hhi;
      trow0[(lg*4 + rg)*36 + tcol] = hhr;   // stage for transpose
      trow1[(lg*4 + rg)*36 + tcol] = hhi;
    }

    // ---- GEMM2 partial: consume 32-col chunk as K-slice (same-wave LDS, in-order) ----
    if (i & 1) {
      const int ks = ch * 8 + (i >> 1);
      f32x4 w0 = *(const f32x4*)&trow0[l15*36 + lg*8];
      f32x4 w1 = *(const f32x4*)&trow0[l15*36 + lg*8 + 4];
      f32x4 v0 = *(const f32x4*)&trow1[l15*36 + lg*8];
      f32x4 v1 = *(const f32x4*)&trow1[l15*36 + lg*8 + 4];
      i32x4 ar  = pack8bf(w0, w1);
      i32x4 ai  = pack8bf(v0, v1);
      i32x4 nai = ai ^ 0x80008000;
#pragma unroll
      for (int ct = 0; ct < 3; ++ct) {
        i32x4 par = pa4[(ks*3 + ct)*64 + lane];
        i32x4 pai = pa4[((16 + ks)*3 + ct)*64 + lane];
        MFMA16(ah[ct][0], ar,  par);
        MFMA16(ah[ct][0], nai, pai);
        MFMA16(ah[ct][1], ar,  pai);
        MFMA16(ah[ct][1], ai,  par);
      }
    }
  }

  asm volatile("s_nop 7\n\ts_nop 7"
               : "+v"(ah[0][0]), "+v"(ah[0][1]), "+v"(ah[1][0]),
                 "+v"(ah[1][1]), "+v"(ah[2][0]), "+v"(ah[2][1]));

  // combine the two col-half partials of h via atomics into pre-zeroed out z-slots
#pragma unroll
  for (int ct = 0; ct < 3; ++ct) {
#pragma unroll
    for (int rg = 0; rg < 4; ++rg) {
      const int row = rbase + lg*4 + rg;
      atomicAdd(&out[(size_t)row*KK + ct*16 + l15], ah[ct][0][rg]);
      atomicAdd(&out[(size_t)(BATCH_*KK) + (size_t)row*KK + ct*16 + l15], ah[ct][1][rg]);
    }
  }

  // per-wave deriv partials (no block reduction needed)
  float rr = waveRed(dsr), ri = waveRed(dsi);
  if (lane == 0) {
    const int w = blockIdx.x * 4 + wave;
    bpart[2*w]     = rr;
    bpart[2*w + 1] = ri;
  }
}

// ---------------- b reduce (8192 wave-partials) ----------------
__global__ void lamp_bred(const float* __restrict__ bpart, float* __restrict__ bval)
{
  float sr = 0.f, si = 0.f;
  for (int m = threadIdx.x; m < 8192; m += 256) { sr += bpart[2*m]; si += bpart[2*m + 1]; }
  __shared__ float red[8];
  sr = waveRed(sr); si = waveRed(si);
  int wave = threadIdx.x >> 6, lane = threadIdx.x & 63;
  if (lane == 0) { red[wave] = sr; red[4 + wave] = si; }
  __syncthreads();
  if (threadIdx.x == 0) {
    bval[0] = (red[0]+red[1]+red[2]+red[3]) / (float)KK;
    bval[1] = (red[4]+red[5]+red[6]+red[7]) / (float)KK;
  }
}

// ---------------- z_new (in-place over accumulated h) ----------------
__global__ void lamp_znew(const float* __restrict__ ur, const float* __restrict__ ui,
                          const float* __restrict__ zr, const float* __restrict__ zi,
                          const float* __restrict__ bval, float* __restrict__ out)
{
  const float br = bval[0], bi = bval[1];
  const int n4 = BATCH_*KK/4;
  const f32x4* u4r = (const f32x4*)ur; const f32x4* u4i = (const f32x4*)ui;
  const f32x4* z4r = (const f32x4*)zr; const f32x4* z4i = (const f32x4*)zi;
  f32x4* o4r = (f32x4*)out;
  f32x4* o4i = (f32x4*)(out + BATCH_*KK);
  for (int i = blockIdx.x*blockDim.x + threadIdx.x; i < n4; i += gridDim.x*blockDim.x) {
    f32x4 h = o4r[i];
    o4r[i] = u4r[i] - h + br * z4r[i];
    f32x4 h2 = o4i[i];
    o4i[i] = u4i[i] - h2 + bi * z4i[i];
  }
}

extern "C" void kernel_launch(void* const* d_in, const int* in_sizes, int n_in,
                              void* d_out, int out_size, void* d_ws, size_t ws_size,
                              hipStream_t stream)
{
  const float* ur  = (const float*)d_in[0];
  const float* ui  = (const float*)d_in[1];
  const float* zr  = (const float*)d_in[2];
  const float* zi  = (const float*)d_in[3];
  const float* Hr  = (const float*)d_in[4];
  const float* Hi  = (const float*)d_in[5];
  const float* Bre = (const float*)d_in[6];
  const float* Bim = (const float*)d_in[7];
  const float* Are = (const float*)d_in[8];
  const float* Aim = (const float*)d_in[9];
  const float* th  = (const float*)d_in[10];
  float* out = (float*)d_out;
  char* ws = (char*)d_ws;
  unsigned short* pb  = (unsigned short*)(ws + WS_PB);
  unsigned short* pa  = (unsigned short*)(ws + WS_PA);
  float* sigp  = (float*)(ws + WS_SIGP);
  float* sigv  = (float*)(ws + WS_SIGMA);
  float* bpart = (float*)(ws + WS_BPART);
  float* bval  = (float*)(ws + WS_BVAL);

  // zero the z-slots of out: they receive h via atomicAdd (2 contributions each)
  hipMemsetAsync(out, 0, (size_t)(2*BATCH_*KK) * sizeof(float), stream);

  hipLaunchKernelGGL(lamp_pack,   dim3(448),  dim3(256), 0, stream, Bre, Bim, Are, Aim, pb, pa);
  hipLaunchKernelGGL(lamp_sig,    dim3(256),  dim3(256), 0, stream, zr, zi, sigp);
  hipLaunchKernelGGL(lamp_sigfin, dim3(1),    dim3(256), 0, stream, sigp, sigv);
  hipLaunchKernelGGL(lamp_main,   dim3(2048), dim3(256), 0, stream,
                     zr, zi, Hr, Hi, pb, pa, sigv, th, out, bpart);
  hipLaunchKernelGGL(lamp_bred,   dim3(1),    dim3(256), 0, stream, bpart, bval);
  hipLaunchKernelGGL(lamp_znew,   dim3(1024), dim3(256), 0, stream, ur, ui, zr, zi, bval, out);
}

// Round 4
// 232.532 us; speedup vs baseline: 2.2393x; 1.0327x over previous
//
#include <hip/hip_runtime.h>
#include <math.h>

#define BATCH_ 65536
#define NN 512
#define KK 48
#define OFF_HHRE (2*BATCH_*KK)            // 6291456
#define OFF_HHIM (OFF_HHRE + BATCH_*NN)   // 39845888

typedef float f32x4 __attribute__((ext_vector_type(4)));
typedef int   i32x4 __attribute__((ext_vector_type(4)));

// ---- ws layout (byte offsets) ----
#define WS_PB    0u         // 2*32*2*512 bf16 = 262144 B
#define WS_PA    262144u    // 2*16*3*512 bf16 =  98304 B (ends 360448)
#define WS_SIGP  393216u    // 256 f32
#define WS_SIGMA 394240u    // 1 f32
#define WS_BPART 395264u    // 4096*2 f32 = 32 KB (ends 428032)
#define WS_BVAL  428032u    // 2 f32

__device__ __forceinline__ unsigned short f2bf(float x) {
  unsigned u = __builtin_bit_cast(unsigned, x);
  unsigned r = (u + 0x7fffu + ((u >> 16) & 1u)) >> 16;
  return (unsigned short)r;
}
__device__ __forceinline__ int pack2bf(float a, float b) {
  return (int)f2bf(a) | ((int)f2bf(b) << 16);
}
__device__ __forceinline__ i32x4 pack8bf(f32x4 a, f32x4 b) {
  i32x4 r;
  r.x = pack2bf(a.x, a.y); r.y = pack2bf(a.z, a.w);
  r.z = pack2bf(b.x, b.y); r.w = pack2bf(b.z, b.w);
  return r;
}
__device__ __forceinline__ float waveRed(float v) {
#pragma unroll
  for (int o = 32; o > 0; o >>= 1) v += __shfl_down(v, o);
  return v;
}

// inline-asm MFMA; s_nop 1 covers VALU-write -> MFMA-read SrcA/B hazard.
#define MFMA16(acc, a, b) \
  asm volatile("s_nop 1\n\tv_mfma_f32_16x16x32_bf16 %0, %1, %2, %0" \
               : "+v"(acc) : "v"(a), "v"(b))

// ---------------- pack B/A into fragment-ordered bf16 ----------------
// PB[mat][nt:32][ks:2][lane:64][j:8] = B_mat[nt*16 + (l&15)][ks*32+(l>>4)*8+j], 0 pad k>=48
// PA[mat][ks:16][ct:3][lane:64][j:8] = A_mat[ks*32+(l>>4)*8+j][ct*16 + (l&15)]
__global__ void lamp_pack(const float* __restrict__ Bre, const float* __restrict__ Bim,
                          const float* __restrict__ Are, const float* __restrict__ Aim,
                          unsigned short* __restrict__ pb, unsigned short* __restrict__ pa)
{
  int i = blockIdx.x * 256 + threadIdx.x;
  const int NPB = 2*32*2*512;   // 65536
  const int NPA = 2*16*3*512;   // 49152
  if (i < NPB) {
    int j = i & 7, l = (i >> 3) & 63, ks = (i >> 9) & 1, nt = (i >> 10) & 31, mat = i >> 15;
    int k = ks*32 + (l >> 4)*8 + j;
    int n = nt*16 + (l & 15);
    float v = 0.f;
    if (k < KK) v = mat ? Bim[n*KK + k] : Bre[n*KK + k];
    pb[i] = f2bf(v);
  } else if (i < NPB + NPA) {
    int i2 = i - NPB;
    int j = i2 & 7, l = (i2 >> 3) & 63;
    int rem = i2 >> 9;          // (mat*16+ks)*3 + ct
    int ct = rem % 3; rem /= 3;
    int ks = rem & 15; int mat = rem >> 4;
    int k = ks*32 + (l >> 4)*8 + j;
    int c = ct*16 + (l & 15);
    float v = mat ? Aim[k*KK + c] : Are[k*KK + c];
    pa[i2] = f2bf(v);
  }
}

// ---------------- sigma ----------------
__global__ void lamp_sig(const float* __restrict__ zr, const float* __restrict__ zi,
                         float* __restrict__ part)
{
  const int n4 = BATCH_*KK/4;
  const f32x4* a = (const f32x4*)zr; const f32x4* b = (const f32x4*)zi;
  float s = 0.f;
  for (int i = blockIdx.x*blockDim.x + threadIdx.x; i < n4; i += gridDim.x*blockDim.x) {
    f32x4 x = a[i]; s += x.x*x.x + x.y*x.y + x.z*x.z + x.w*x.w;
    f32x4 y = b[i]; s += y.x*y.x + y.y*y.y + y.z*y.z + y.w*y.w;
  }
  __shared__ float red[4];
  s = waveRed(s);
  int wave = threadIdx.x >> 6, lane = threadIdx.x & 63;
  if (lane == 0) red[wave] = s;
  __syncthreads();
  if (threadIdx.x == 0) part[blockIdx.x] = red[0]+red[1]+red[2]+red[3];
}

__global__ void lamp_sigfin(const float* __restrict__ part, float* __restrict__ sig)
{
  float s = part[threadIdx.x];   // 256 partials
  __shared__ float red[4];
  s = waveRed(s);
  int wave = threadIdx.x >> 6, lane = threadIdx.x & 63;
  if (lane == 0) red[wave] = s;
  __syncthreads();
  if (threadIdx.x == 0) sig[0] = sqrtf(red[0]+red[1]+red[2]+red[3]) / sqrtf((float)KK);
}

// ---------------- main fused kernel ----------------
// R1 structure (1024 blocks, wave owns 16 rows x all 32 col-tiles; no atomics).
// New in R4: cross-iteration double-buffered H prefetch (hide HBM latency
// inside the wave, since occupancy is VGPR-capped at ~4 waves/SIMD) and
// nontemporal Hh stores (stop evicting H_hat from L3).
#define PREF(n, hR, hI) do { \
  const size_t o_ = (size_t)(n) * 16; \
  hR[0]=hrB[o_];      hR[1]=hrB[o_+NN];   hR[2]=hrB[o_+2*NN]; hR[3]=hrB[o_+3*NN]; \
  hI[0]=hiB[o_];      hI[1]=hiB[o_+NN];   hI[2]=hiB[o_+2*NN]; hI[3]=hiB[o_+3*NN]; \
} while(0)

#define ITER(n0, hRc, hIc, NPREF, hRn, hIn) do { \
  i32x4 br0 = pb4[((n0)*2 + 0)*64 + lane]; \
  i32x4 br1 = pb4[((n0)*2 + 1)*64 + lane]; \
  i32x4 bi0 = pb4[((32 + (n0))*2 + 0)*64 + lane]; \
  i32x4 bi1 = pb4[((32 + (n0))*2 + 1)*64 + lane]; \
  PREF(NPREF, hRn, hIn); \
  i32x4 nzi0 = zi[0] ^ 0x80008000, nzi1 = zi[1] ^ 0x80008000; \
  f32x4 accR = (f32x4){0,0,0,0}, accI = (f32x4){0,0,0,0}; \
  MFMA16(accR, zr[0], br0);  MFMA16(accR, zr[1], br1); \
  MFMA16(accR, nzi0,  bi0);  MFMA16(accR, nzi1,  bi1); \
  MFMA16(accI, zr[0], bi0);  MFMA16(accI, zr[1], bi1); \
  MFMA16(accI, zi[0], br0);  MFMA16(accI, zi[1], br1); \
  asm volatile("s_nop 7\n\ts_nop 7" : "+v"(accR), "+v"(accI)); \
  const size_t ob_ = (size_t)(n0) * 16; \
  const int tcol_ = ((n0) & 1) * 16 + l15; \
  _Pragma("unroll") \
  for (int rg = 0; rg < 4; ++rg) { \
    float re = accR[rg] + hRc[rg]; \
    float im = accI[rg] + hIc[rg]; \
    float er = __expf(re*re*nhalf_inv_s2); \
    float ei = __expf(im*im*nhalf_inv_s2); \
    float t2er = t2*er, t2ei = t2*ei; \
    float hhr = t1*re + re*t2er; \
    float hhi = t1*im + im*t2ei; \
    dsr += t1 + t2er*(1.f - re*re*inv_s2); \
    dsi += t1 + t2ei*(1.f - im*im*inv_s2); \
    __builtin_nontemporal_store(hhr, &oRB[ob_ + (size_t)rg*NN]); \
    __builtin_nontemporal_store(hhi, &oIB[ob_ + (size_t)rg*NN]); \
    trow0[(lg*4 + rg)*36 + tcol_] = hhr; \
    trow1[(lg*4 + rg)*36 + tcol_] = hhi; \
  } \
  if ((n0) & 1) { \
    const int ks = (n0) >> 1; \
    f32x4 w0 = *(const f32x4*)&trow0[l15*36 + lg*8]; \
    f32x4 w1 = *(const f32x4*)&trow0[l15*36 + lg*8 + 4]; \
    f32x4 v0 = *(const f32x4*)&trow1[l15*36 + lg*8]; \
    f32x4 v1 = *(const f32x4*)&trow1[l15*36 + lg*8 + 4]; \
    i32x4 ar  = pack8bf(w0, w1); \
    i32x4 ai  = pack8bf(v0, v1); \
    i32x4 nai = ai ^ 0x80008000; \
    _Pragma("unroll") \
    for (int ct = 0; ct < 3; ++ct) { \
      i32x4 par = pa4[(ks*3 + ct)*64 + lane]; \
      i32x4 pai = pa4[((16 + ks)*3 + ct)*64 + lane]; \
      MFMA16(ah[ct][0], ar,  par); \
      MFMA16(ah[ct][0], nai, pai); \
      MFMA16(ah[ct][1], ar,  pai); \
      MFMA16(ah[ct][1], ai,  par); \
    } \
  } \
} while(0)

__global__ __launch_bounds__(256, 4) void lamp_main(
    const float* __restrict__ zre, const float* __restrict__ zim,
    const float* __restrict__ Hre, const float* __restrict__ Him,
    const unsigned short* __restrict__ pb, const unsigned short* __restrict__ pa,
    const float* __restrict__ sigp, const float* __restrict__ theta,
    float* __restrict__ out, float* __restrict__ bpart)
{
  __shared__ float tbuf[4][2][16*36];   // per-wave transpose buffer, stride 36 (bank-clean)
  __shared__ float red[8];

  const int tid = threadIdx.x;
  const int wave = tid >> 6, lane = tid & 63;
  const int l15 = lane & 15, lg = lane >> 4;
  const int rbase = blockIdx.x * 64 + wave * 16;
  const int row0 = rbase + lg*4;

  const float t0 = theta[0], t1 = theta[1], t2 = theta[2];
  const float sigma = sigp[0];
  const float s2 = (t0 * sigma) * (t0 * sigma);
  const float inv_s2 = 1.0f / s2;
  const float nhalf_inv_s2 = -0.5f * inv_s2;

  // z fragments (A operand of GEMM1), K padded 48->64
  i32x4 zr[2], zi[2];
  {
    const int myrow = rbase + l15;
    const float* pr = zre + (size_t)myrow * KK;
    const float* pi = zim + (size_t)myrow * KK;
#pragma unroll
    for (int ks = 0; ks < 2; ++ks) {
      const int k0 = ks*32 + lg*8;
      f32x4 a0 = {0,0,0,0}, a1 = {0,0,0,0}, b0 = {0,0,0,0}, b1 = {0,0,0,0};
      if (k0 < KK) {
        a0 = *(const f32x4*)(pr + k0); a1 = *(const f32x4*)(pr + k0 + 4);
        b0 = *(const f32x4*)(pi + k0); b1 = *(const f32x4*)(pi + k0 + 4);
      }
      zr[ks] = pack8bf(a0, a1);
      zi[ks] = pack8bf(b0, b1);
    }
  }

  const i32x4* pb4 = (const i32x4*)pb;
  const i32x4* pa4 = (const i32x4*)pa;

  const float* hrB = Hre + (size_t)row0 * NN + l15;
  const float* hiB = Him + (size_t)row0 * NN + l15;
  float* oRB = out + OFF_HHRE + (size_t)row0 * NN + l15;
  float* oIB = out + OFF_HHIM + (size_t)row0 * NN + l15;

  f32x4 ah[3][2];
#pragma unroll
  for (int c = 0; c < 3; ++c) {
    ah[c][0] = (f32x4){0,0,0,0};
    ah[c][1] = (f32x4){0,0,0,0};
  }

  float dsr = 0.f, dsi = 0.f;
  float* trow0 = &tbuf[wave][0][0];
  float* trow1 = &tbuf[wave][1][0];

  float hRa[4], hIa[4], hRb[4], hIb[4];
  PREF(0, hRa, hIa);          // prologue: prefetch col-tile 0

#pragma unroll 1
  for (int t = 0; t < 16; ++t) {
    ITER(2*t,     hRa, hIa, 2*t + 1, hRb, hIb);
    const int nn = (2*t + 2 < 32) ? (2*t + 2) : 31;   // clamped dummy on last iter
    ITER(2*t + 1, hRb, hIb, nn,      hRa, hIa);
  }

  asm volatile("s_nop 7\n\ts_nop 7"
               : "+v"(ah[0][0]), "+v"(ah[0][1]), "+v"(ah[1][0]),
                 "+v"(ah[1][1]), "+v"(ah[2][0]), "+v"(ah[2][1]));

  // h written directly (single owner per row-tile, no atomics)
#pragma unroll
  for (int ct = 0; ct < 3; ++ct) {
#pragma unroll
    for (int rg = 0; rg < 4; ++rg) {
      const int row = rbase + lg*4 + rg;
      out[(size_t)row*KK + ct*16 + l15] = ah[ct][0][rg];
      out[(size_t)(BATCH_*KK) + (size_t)row*KK + ct*16 + l15] = ah[ct][1][rg];
    }
  }

  // per-wave deriv partials (4096 waves)
  float rr = waveRed(dsr), ri = waveRed(dsi);
  if (lane == 0) {
    const int w = blockIdx.x * 4 + wave;
    bpart[2*w]     = rr;
    bpart[2*w + 1] = ri;
  }
  (void)red;
}

// ---------------- b reduce (4096 wave-partials) ----------------
__global__ void lamp_bred(const float* __restrict__ bpart, float* __restrict__ bval)
{
  float sr = 0.f, si = 0.f;
  for (int m = threadIdx.x; m < 4096; m += 256) { sr += bpart[2*m]; si += bpart[2*m + 1]; }
  __shared__ float red[8];
  sr = waveRed(sr); si = waveRed(si);
  int wave = threadIdx.x >> 6, lane = threadIdx.x & 63;
  if (lane == 0) { red[wave] = sr; red[4 + wave] = si; }
  __syncthreads();
  if (threadIdx.x == 0) {
    bval[0] = (red[0]+red[1]+red[2]+red[3]) / (float)KK;
    bval[1] = (red[4]+red[5]+red[6]+red[7]) / (float)KK;
  }
}

// ---------------- z_new (in-place over parked h) ----------------
__global__ void lamp_znew(const float* __restrict__ ur, const float* __restrict__ ui,
                          const float* __restrict__ zr, const float* __restrict__ zi,
                          const float* __restrict__ bval, float* __restrict__ out)
{
  const float br = bval[0], bi = bval[1];
  const int n4 = BATCH_*KK/4;
  const f32x4* u4r = (const f32x4*)ur; const f32x4* u4i = (const f32x4*)ui;
  const f32x4* z4r = (const f32x4*)zr; const f32x4* z4i = (const f32x4*)zi;
  f32x4* o4r = (f32x4*)out;
  f32x4* o4i = (f32x4*)(out + BATCH_*KK);
  for (int i = blockIdx.x*blockDim.x + threadIdx.x; i < n4; i += gridDim.x*blockDim.x) {
    f32x4 h = o4r[i];
    o4r[i] = u4r[i] - h + br * z4r[i];
    f32x4 h2 = o4i[i];
    o4i[i] = u4i[i] - h2 + bi * z4i[i];
  }
}

extern "C" void kernel_launch(void* const* d_in, const int* in_sizes, int n_in,
                              void* d_out, int out_size, void* d_ws, size_t ws_size,
                              hipStream_t stream)
{
  const float* ur  = (const float*)d_in[0];
  const float* ui  = (const float*)d_in[1];
  const float* zr  = (const float*)d_in[2];
  const float* zi  = (const float*)d_in[3];
  const float* Hr  = (const float*)d_in[4];
  const float* Hi  = (const float*)d_in[5];
  const float* Bre = (const float*)d_in[6];
  const float* Bim = (const float*)d_in[7];
  const float* Are = (const float*)d_in[8];
  const float* Aim = (const float*)d_in[9];
  const float* th  = (const float*)d_in[10];
  float* out = (float*)d_out;
  char* ws = (char*)d_ws;
  unsigned short* pb  = (unsigned short*)(ws + WS_PB);
  unsigned short* pa  = (unsigned short*)(ws + WS_PA);
  float* sigp  = (float*)(ws + WS_SIGP);
  float* sigv  = (float*)(ws + WS_SIGMA);
  float* bpart = (float*)(ws + WS_BPART);
  float* bval  = (float*)(ws + WS_BVAL);

  hipLaunchKernelGGL(lamp_pack,   dim3(448),  dim3(256), 0, stream, Bre, Bim, Are, Aim, pb, pa);
  hipLaunchKernelGGL(lamp_sig,    dim3(256),  dim3(256), 0, stream, zr, zi, sigp);
  hipLaunchKernelGGL(lamp_sigfin, dim3(1),    dim3(256), 0, stream, sigp, sigv);
  hipLaunchKernelGGL(lamp_main,   dim3(1024), dim3(256), 0, stream,
                     zr, zi, Hr, Hi, pb, pa, sigv, th, out, bpart);
  hipLaunchKernelGGL(lamp_bred,   dim3(1),    dim3(256), 0, stream, bpart, bval);
  hipLaunchKernelGGL(lamp_znew,   dim3(1024), dim3(256), 0, stream, ur, ui, zr, zi, bval, out);
}

// Round 5
// 228.167 us; speedup vs baseline: 2.2821x; 1.0191x over previous
//
#include <hip/hip_runtime.h>
#include <math.h>

#define BATCH_ 65536
#define NN 512
#define KK 48
#define OFF_HHRE (2*BATCH_*KK)            // 6291456
#define OFF_HHIM (OFF_HHRE + BATCH_*NN)   // 39845888

typedef float f32x4 __attribute__((ext_vector_type(4)));
typedef int   i32x4 __attribute__((ext_vector_type(4)));

// ---- ws layout (byte offsets) ----
#define WS_PB    0u         // 2*32*2*512 bf16 = 262144 B
#define WS_PA    262144u    // 2*16*3*512 bf16 =  98304 B (ends 360448)
#define WS_SIGP  393216u    // 256 f32
#define WS_SIGMA 394240u    // 1 f32
#define WS_BPART 395264u    // 4096*2 f32 = 32 KB (ends 428032)
#define WS_BVAL  428032u    // 2 f32

__device__ __forceinline__ unsigned short f2bf(float x) {
  unsigned u = __builtin_bit_cast(unsigned, x);
  unsigned r = (u + 0x7fffu + ((u >> 16) & 1u)) >> 16;
  return (unsigned short)r;
}
__device__ __forceinline__ int pack2bf(float a, float b) {
  return (int)f2bf(a) | ((int)f2bf(b) << 16);
}
__device__ __forceinline__ i32x4 pack8bf(f32x4 a, f32x4 b) {
  i32x4 r;
  r.x = pack2bf(a.x, a.y); r.y = pack2bf(a.z, a.w);
  r.z = pack2bf(b.x, b.y); r.w = pack2bf(b.z, b.w);
  return r;
}
__device__ __forceinline__ float waveRed(float v) {
#pragma unroll
  for (int o = 32; o > 0; o >>= 1) v += __shfl_down(v, o);
  return v;
}

// inline-asm MFMA; s_nop 1 covers VALU-write -> MFMA-read SrcA/B hazard.
#define MFMA16(acc, a, b) \
  asm volatile("s_nop 1\n\tv_mfma_f32_16x16x32_bf16 %0, %1, %2, %0" \
               : "+v"(acc) : "v"(a), "v"(b))

// ---------------- pack B/A into fragment-ordered bf16 ----------------
// PB[mat][nt:32][ks:2][lane:64][j:8] = B_mat[nt*16 + (l&15)][ks*32+(l>>4)*8+j], 0 pad k>=48
// PA[mat][ks:16][ct:3][lane:64][j:8] = A_mat[ks*32+(l>>4)*8+j][ct*16 + (l&15)]
__global__ void lamp_pack(const float* __restrict__ Bre, const float* __restrict__ Bim,
                          const float* __restrict__ Are, const float* __restrict__ Aim,
                          unsigned short* __restrict__ pb, unsigned short* __restrict__ pa)
{
  int i = blockIdx.x * 256 + threadIdx.x;
  const int NPB = 2*32*2*512;   // 65536
  const int NPA = 2*16*3*512;   // 49152
  if (i < NPB) {
    int j = i & 7, l = (i >> 3) & 63, ks = (i >> 9) & 1, nt = (i >> 10) & 31, mat = i >> 15;
    int k = ks*32 + (l >> 4)*8 + j;
    int n = nt*16 + (l & 15);
    float v = 0.f;
    if (k < KK) v = mat ? Bim[n*KK + k] : Bre[n*KK + k];
    pb[i] = f2bf(v);
  } else if (i < NPB + NPA) {
    int i2 = i - NPB;
    int j = i2 & 7, l = (i2 >> 3) & 63;
    int rem = i2 >> 9;          // (mat*16+ks)*3 + ct
    int ct = rem % 3; rem /= 3;
    int ks = rem & 15; int mat = rem >> 4;
    int k = ks*32 + (l >> 4)*8 + j;
    int c = ct*16 + (l & 15);
    float v = mat ? Aim[k*KK + c] : Are[k*KK + c];
    pa[i2] = f2bf(v);
  }
}

// ---------------- sigma ----------------
__global__ void lamp_sig(const float* __restrict__ zr, const float* __restrict__ zi,
                         float* __restrict__ part)
{
  const int n4 = BATCH_*KK/4;
  const f32x4* a = (const f32x4*)zr; const f32x4* b = (const f32x4*)zi;
  float s = 0.f;
  for (int i = blockIdx.x*blockDim.x + threadIdx.x; i < n4; i += gridDim.x*blockDim.x) {
    f32x4 x = a[i]; s += x.x*x.x + x.y*x.y + x.z*x.z + x.w*x.w;
    f32x4 y = b[i]; s += y.x*y.x + y.y*y.y + y.z*y.z + y.w*y.w;
  }
  __shared__ float red[4];
  s = waveRed(s);
  int wave = threadIdx.x >> 6, lane = threadIdx.x & 63;
  if (lane == 0) red[wave] = s;
  __syncthreads();
  if (threadIdx.x == 0) part[blockIdx.x] = red[0]+red[1]+red[2]+red[3];
}

__global__ void lamp_sigfin(const float* __restrict__ part, float* __restrict__ sig)
{
  float s = part[threadIdx.x];   // 256 partials
  __shared__ float red[4];
  s = waveRed(s);
  int wave = threadIdx.x >> 6, lane = threadIdx.x & 63;
  if (lane == 0) red[wave] = s;
  __syncthreads();
  if (threadIdx.x == 0) sig[0] = sqrtf(red[0]+red[1]+red[2]+red[3]) / sqrtf((float)KK);
}

// ---------------- main fused kernel ----------------
// R5: all HBM traffic dwordx4. MFMA Z acc -> LDS (fragment layout, scalar
// ds_write) -> re-read as float4 rows (lane q=lane>>2 owns row q, quad
// p=lane&3). H loads + NT Hh stores are f32x4, H prefetched 2 iterations
// deep. Hh written back to same LDS slot in float4 layout feeds GEMM2
// fragment reads. DS ops are in-order per wave -> no barriers needed.
#define ITER(n0, hRc, hIc, NPREF, doPref) do { \
  i32x4 br0 = pb4[((n0)*2 + 0)*64 + lane]; \
  i32x4 br1 = pb4[((n0)*2 + 1)*64 + lane]; \
  i32x4 bi0 = pb4[((32 + (n0))*2 + 0)*64 + lane]; \
  i32x4 bi1 = pb4[((32 + (n0))*2 + 1)*64 + lane]; \
  i32x4 nzi0 = zi[0] ^ 0x80008000, nzi1 = zi[1] ^ 0x80008000; \
  f32x4 accR = (f32x4){0,0,0,0}, accI = (f32x4){0,0,0,0}; \
  MFMA16(accR, zr[0], br0);  MFMA16(accR, zr[1], br1); \
  MFMA16(accR, nzi0,  bi0);  MFMA16(accR, nzi1,  bi1); \
  MFMA16(accI, zr[0], bi0);  MFMA16(accI, zr[1], bi1); \
  MFMA16(accI, zi[0], br0);  MFMA16(accI, zi[1], br1); \
  asm volatile("s_nop 7\n\ts_nop 7" : "+v"(accR), "+v"(accI)); \
  const int zcol_ = ((n0) & 1)*16 + l15; \
  _Pragma("unroll") \
  for (int rg = 0; rg < 4; ++rg) { \
    trow0[(lg*4 + rg)*36 + zcol_] = accR[rg]; \
    trow1[(lg*4 + rg)*36 + zcol_] = accI[rg]; \
  } \
  asm volatile("" ::: "memory"); \
  const int lcol_ = ((n0) & 1)*16 + p4; \
  f32x4 re = *(const f32x4*)&trow0[q36 + lcol_]; \
  f32x4 im = *(const f32x4*)&trow1[q36 + lcol_]; \
  re += hRc;  im += hIc; \
  if (doPref) { \
    hRc = *(const f32x4*)(hrB + (size_t)(NPREF)*16); \
    hIc = *(const f32x4*)(hiB + (size_t)(NPREF)*16); \
  } \
  f32x4 hhr, hhi; \
  _Pragma("unroll") \
  for (int c = 0; c < 4; ++c) { \
    float rec = re[c], imc = im[c]; \
    float er = __expf(rec*rec*nhalf_inv_s2); \
    float ei = __expf(imc*imc*nhalf_inv_s2); \
    float t2er = t2*er, t2ei = t2*ei; \
    hhr[c] = t1*rec + rec*t2er; \
    hhi[c] = t1*imc + imc*t2ei; \
    dsr += t1 + t2er*(1.f - rec*rec*inv_s2); \
    dsi += t1 + t2ei*(1.f - imc*imc*inv_s2); \
  } \
  __builtin_nontemporal_store(hhr, (f32x4*)(oRB + (size_t)(n0)*16)); \
  __builtin_nontemporal_store(hhi, (f32x4*)(oIB + (size_t)(n0)*16)); \
  *(f32x4*)&trow0[q36 + lcol_] = hhr; \
  *(f32x4*)&trow1[q36 + lcol_] = hhi; \
  asm volatile("" ::: "memory"); \
  if ((n0) & 1) { \
    const int ks = (n0) >> 1; \
    f32x4 w0 = *(const f32x4*)&trow0[l15*36 + lg*8]; \
    f32x4 w1 = *(const f32x4*)&trow0[l15*36 + lg*8 + 4]; \
    f32x4 v0 = *(const f32x4*)&trow1[l15*36 + lg*8]; \
    f32x4 v1 = *(const f32x4*)&trow1[l15*36 + lg*8 + 4]; \
    i32x4 ar  = pack8bf(w0, w1); \
    i32x4 ai  = pack8bf(v0, v1); \
    i32x4 nai = ai ^ 0x80008000; \
    _Pragma("unroll") \
    for (int ct = 0; ct < 3; ++ct) { \
      i32x4 par = pa4[(ks*3 + ct)*64 + lane]; \
      i32x4 pai = pa4[((16 + ks)*3 + ct)*64 + lane]; \
      MFMA16(ah[ct][0], ar,  par); \
      MFMA16(ah[ct][0], nai, pai); \
      MFMA16(ah[ct][1], ar,  pai); \
      MFMA16(ah[ct][1], ai,  par); \
    } \
  } \
} while(0)

__global__ __launch_bounds__(256, 4) void lamp_main(
    const float* __restrict__ zre, const float* __restrict__ zim,
    const float* __restrict__ Hre, const float* __restrict__ Him,
    const unsigned short* __restrict__ pb, const unsigned short* __restrict__ pa,
    const float* __restrict__ sigp, const float* __restrict__ theta,
    float* __restrict__ out, float* __restrict__ bpart)
{
  __shared__ __align__(16) float tbuf[4][2][16*36];  // per-wave, stride 36
  __shared__ float red[8];

  const int tid = threadIdx.x;
  const int wave = tid >> 6, lane = tid & 63;
  const int l15 = lane & 15, lg = lane >> 4;
  const int q = lane >> 2, p4 = (lane & 3) * 4;      // float4 row/quad mapping
  const int q36 = q * 36;
  const int rbase = blockIdx.x * 64 + wave * 16;

  const float t0 = theta[0], t1 = theta[1], t2 = theta[2];
  const float sigma = sigp[0];
  const float s2 = (t0 * sigma) * (t0 * sigma);
  const float inv_s2 = 1.0f / s2;
  const float nhalf_inv_s2 = -0.5f * inv_s2;

  // z fragments (A operand of GEMM1), K padded 48->64
  i32x4 zr[2], zi[2];
  {
    const int myrow = rbase + l15;
    const float* pr = zre + (size_t)myrow * KK;
    const float* pi = zim + (size_t)myrow * KK;
#pragma unroll
    for (int ks = 0; ks < 2; ++ks) {
      const int k0 = ks*32 + lg*8;
      f32x4 a0 = {0,0,0,0}, a1 = {0,0,0,0}, b0 = {0,0,0,0}, b1 = {0,0,0,0};
      if (k0 < KK) {
        a0 = *(const f32x4*)(pr + k0); a1 = *(const f32x4*)(pr + k0 + 4);
        b0 = *(const f32x4*)(pi + k0); b1 = *(const f32x4*)(pi + k0 + 4);
      }
      zr[ks] = pack8bf(a0, a1);
      zi[ks] = pack8bf(b0, b1);
    }
  }

  const i32x4* pb4 = (const i32x4*)pb;
  const i32x4* pa4 = (const i32x4*)pa;

  // float4 bases: lane owns row rbase+q, columns p4..p4+3 of each 16-col tile
  const float* hrB = Hre + (size_t)(rbase + q) * NN + p4;
  const float* hiB = Him + (size_t)(rbase + q) * NN + p4;
  float* oRB = out + OFF_HHRE + (size_t)(rbase + q) * NN + p4;
  float* oIB = out + OFF_HHIM + (size_t)(rbase + q) * NN + p4;

  f32x4 ah[3][2];
#pragma unroll
  for (int c = 0; c < 3; ++c) {
    ah[c][0] = (f32x4){0,0,0,0};
    ah[c][1] = (f32x4){0,0,0,0};
  }

  float dsr = 0.f, dsi = 0.f;
  float* trow0 = &tbuf[wave][0][0];
  float* trow1 = &tbuf[wave][1][0];

  // prologue: prefetch H tiles 0 and 1 (distance-2 pipeline, 2 buffers)
  f32x4 hRa = *(const f32x4*)(hrB);
  f32x4 hIa = *(const f32x4*)(hiB);
  f32x4 hRb = *(const f32x4*)(hrB + 16);
  f32x4 hIb = *(const f32x4*)(hiB + 16);

#pragma unroll 1
  for (int t = 0; t < 16; ++t) {
    const int na = (2*t + 2 < 32) ? (2*t + 2) : 31;
    const int nb = (2*t + 3 < 32) ? (2*t + 3) : 31;
    ITER(2*t,     hRa, hIa, na, 1);
    ITER(2*t + 1, hRb, hIb, nb, 1);
  }

  asm volatile("s_nop 7\n\ts_nop 7"
               : "+v"(ah[0][0]), "+v"(ah[0][1]), "+v"(ah[1][0]),
                 "+v"(ah[1][1]), "+v"(ah[2][0]), "+v"(ah[2][1]));

  // h written directly (single owner per row-tile)
#pragma unroll
  for (int ct = 0; ct < 3; ++ct) {
#pragma unroll
    for (int rg = 0; rg < 4; ++rg) {
      const int row = rbase + lg*4 + rg;
      out[(size_t)row*KK + ct*16 + l15] = ah[ct][0][rg];
      out[(size_t)(BATCH_*KK) + (size_t)row*KK + ct*16 + l15] = ah[ct][1][rg];
    }
  }

  // per-wave deriv partials (4096 waves)
  float rr = waveRed(dsr), ri = waveRed(dsi);
  if (lane == 0) {
    const int w = blockIdx.x * 4 + wave;
    bpart[2*w]     = rr;
    bpart[2*w + 1] = ri;
  }
  (void)red;
}

// ---------------- b reduce (4096 wave-partials) ----------------
__global__ void lamp_bred(const float* __restrict__ bpart, float* __restrict__ bval)
{
  float sr = 0.f, si = 0.f;
  for (int m = threadIdx.x; m < 4096; m += 256) { sr += bpart[2*m]; si += bpart[2*m + 1]; }
  __shared__ float red[8];
  sr = waveRed(sr); si = waveRed(si);
  int wave = threadIdx.x >> 6, lane = threadIdx.x & 63;
  if (lane == 0) { red[wave] = sr; red[4 + wave] = si; }
  __syncthreads();
  if (threadIdx.x == 0) {
    bval[0] = (red[0]+red[1]+red[2]+red[3]) / (float)KK;
    bval[1] = (red[4]+red[5]+red[6]+red[7]) / (float)KK;
  }
}

// ---------------- z_new (in-place over parked h) ----------------
__global__ void lamp_znew(const float* __restrict__ ur, const float* __restrict__ ui,
                          const float* __restrict__ zr, const float* __restrict__ zi,
                          const float* __restrict__ bval, float* __restrict__ out)
{
  const float br = bval[0], bi = bval[1];
  const int n4 = BATCH_*KK/4;
  const f32x4* u4r = (const f32x4*)ur; const f32x4* u4i = (const f32x4*)ui;
  const f32x4* z4r = (const f32x4*)zr; const f32x4* z4i = (const f32x4*)zi;
  f32x4* o4r = (f32x4*)out;
  f32x4* o4i = (f32x4*)(out + BATCH_*KK);
  for (int i = blockIdx.x*blockDim.x + threadIdx.x; i < n4; i += gridDim.x*blockDim.x) {
    f32x4 h = o4r[i];
    o4r[i] = u4r[i] - h + br * z4r[i];
    f32x4 h2 = o4i[i];
    o4i[i] = u4i[i] - h2 + bi * z4i[i];
  }
}

extern "C" void kernel_launch(void* const* d_in, const int* in_sizes, int n_in,
                              void* d_out, int out_size, void* d_ws, size_t ws_size,
                              hipStream_t stream)
{
  const float* ur  = (const float*)d_in[0];
  const float* ui  = (const float*)d_in[1];
  const float* zr  = (const float*)d_in[2];
  const float* zi  = (const float*)d_in[3];
  const float* Hr  = (const float*)d_in[4];
  const float* Hi  = (const float*)d_in[5];
  const float* Bre = (const float*)d_in[6];
  const float* Bim = (const float*)d_in[7];
  const float* Are = (const float*)d_in[8];
  const float* Aim = (const float*)d_in[9];
  const float* th  = (const float*)d_in[10];
  float* out = (float*)d_out;
  char* ws = (char*)d_ws;
  unsigned short* pb  = (unsigned short*)(ws + WS_PB);
  unsigned short* pa  = (unsigned short*)(ws + WS_PA);
  float* sigp  = (float*)(ws + WS_SIGP);
  float* sigv  = (float*)(ws + WS_SIGMA);
  float* bpart = (float*)(ws + WS_BPART);
  float* bval  = (float*)(ws + WS_BVAL);

  hipLaunchKernelGGL(lamp_pack,   dim3(448),  dim3(256), 0, stream, Bre, Bim, Are, Aim, pb, pa);
  hipLaunchKernelGGL(lamp_sig,    dim3(256),  dim3(256), 0, stream, zr, zi, sigp);
  hipLaunchKernelGGL(lamp_sigfin, dim3(1),    dim3(256), 0, stream, sigp, sigv);
  hipLaunchKernelGGL(lamp_main,   dim3(1024), dim3(256), 0, stream,
                     zr, zi, Hr, Hi, pb, pa, sigv, th, out, bpart);
  hipLaunchKernelGGL(lamp_bred,   dim3(1),    dim3(256), 0, stream, bpart, bval);
  hipLaunchKernelGGL(lamp_znew,   dim3(1024), dim3(256), 0, stream, ur, ui, zr, zi, bval, out);
}

// Round 6
// 198.002 us; speedup vs baseline: 2.6298x; 1.1523x over previous
//
#include <hip/hip_runtime.h>
#include <math.h>

#define BATCH_ 65536
#define NN 512
#define KK 48
#define OFF_HHRE (2*BATCH_*KK)            // 6291456
#define OFF_HHIM (OFF_HHRE + BATCH_*NN)   // 39845888

typedef float f32x4 __attribute__((ext_vector_type(4)));
typedef int   i32x4 __attribute__((ext_vector_type(4)));
typedef short bf16x8 __attribute__((ext_vector_type(8)));

// ---- ws layout (byte offsets) ----
#define WS_PB    0u         // 2*32*2*512 bf16 = 262144 B
#define WS_PA    262144u    // 2*16*3*512 bf16 =  98304 B (ends 360448)
#define WS_SIGP  393216u    // 256 f32
#define WS_SIGMA 394240u    // 1 f32
#define WS_BPART 395264u    // 4096*2 f32 = 32 KB (ends 428032)
#define WS_BVAL  428032u    // 2 f32

__device__ __forceinline__ unsigned short f2bf(float x) {
  unsigned u = __builtin_bit_cast(unsigned, x);
  unsigned r = (u + 0x7fffu + ((u >> 16) & 1u)) >> 16;
  return (unsigned short)r;
}
__device__ __forceinline__ int pack2bf(float a, float b) {
  return (int)f2bf(a) | ((int)f2bf(b) << 16);
}
__device__ __forceinline__ i32x4 pack8bf(f32x4 a, f32x4 b) {
  i32x4 r;
  r.x = pack2bf(a.x, a.y); r.y = pack2bf(a.z, a.w);
  r.z = pack2bf(b.x, b.y); r.w = pack2bf(b.z, b.w);
  return r;
}
__device__ __forceinline__ float waveRed(float v) {
#pragma unroll
  for (int o = 32; o > 0; o >>= 1) v += __shfl_down(v, o);
  return v;
}

// compiler-scheduled MFMA (no manual s_nop fences)
#define MFMA(acc, A, B) \
  acc = __builtin_amdgcn_mfma_f32_16x16x32_bf16( \
      __builtin_bit_cast(bf16x8, A), __builtin_bit_cast(bf16x8, B), acc, 0, 0, 0)

// ---------------- pack B/A into fragment-ordered bf16 (UNCHANGED layout) ----
// PB[mat][nt:32][ks:2][lane:64][j:8] = B_mat[nt*16 + (l&15)][ks*32+(l>>4)*8+j], 0 pad k>=48
// PA[mat][ks:16][ct:3][lane:64][j:8] = A_mat[ks*32+(l>>4)*8+j][ct*16 + (l&15)]
// In R6 these serve as the A-operand (row = l&15) of the transposed GEMMs.
__global__ void lamp_pack(const float* __restrict__ Bre, const float* __restrict__ Bim,
                          const float* __restrict__ Are, const float* __restrict__ Aim,
                          unsigned short* __restrict__ pb, unsigned short* __restrict__ pa)
{
  int i = blockIdx.x * 256 + threadIdx.x;
  const int NPB = 2*32*2*512;   // 65536
  const int NPA = 2*16*3*512;   // 49152
  if (i < NPB) {
    int j = i & 7, l = (i >> 3) & 63, ks = (i >> 9) & 1, nt = (i >> 10) & 31, mat = i >> 15;
    int k = ks*32 + (l >> 4)*8 + j;
    int n = nt*16 + (l & 15);
    float v = 0.f;
    if (k < KK) v = mat ? Bim[n*KK + k] : Bre[n*KK + k];
    pb[i] = f2bf(v);
  } else if (i < NPB + NPA) {
    int i2 = i - NPB;
    int j = i2 & 7, l = (i2 >> 3) & 63;
    int rem = i2 >> 9;          // (mat*16+ks)*3 + ct
    int ct = rem % 3; rem /= 3;
    int ks = rem & 15; int mat = rem >> 4;
    int k = ks*32 + (l >> 4)*8 + j;
    int c = ct*16 + (l & 15);
    float v = mat ? Aim[k*KK + c] : Are[k*KK + c];
    pa[i2] = f2bf(v);
  }
}

// ---------------- sigma ----------------
__global__ void lamp_sig(const float* __restrict__ zr, const float* __restrict__ zi,
                         float* __restrict__ part)
{
  const int n4 = BATCH_*KK/4;
  const f32x4* a = (const f32x4*)zr; const f32x4* b = (const f32x4*)zi;
  float s = 0.f;
  for (int i = blockIdx.x*blockDim.x + threadIdx.x; i < n4; i += gridDim.x*blockDim.x) {
    f32x4 x = a[i]; s += x.x*x.x + x.y*x.y + x.z*x.z + x.w*x.w;
    f32x4 y = b[i]; s += y.x*y.x + y.y*y.y + y.z*y.z + y.w*y.w;
  }
  __shared__ float red[4];
  s = waveRed(s);
  int wave = threadIdx.x >> 6, lane = threadIdx.x & 63;
  if (lane == 0) red[wave] = s;
  __syncthreads();
  if (threadIdx.x == 0) part[blockIdx.x] = red[0]+red[1]+red[2]+red[3];
}

__global__ void lamp_sigfin(const float* __restrict__ part, float* __restrict__ sig)
{
  float s = part[threadIdx.x];   // 256 partials
  __shared__ float red[4];
  s = waveRed(s);
  int wave = threadIdx.x >> 6, lane = threadIdx.x & 63;
  if (lane == 0) red[wave] = s;
  __syncthreads();
  if (threadIdx.x == 0) sig[0] = sqrtf(red[0]+red[1]+red[2]+red[3]) / sqrtf((float)KK);
}

// ---------------- main fused kernel (R6: transposed GEMMs, zero LDS) -------
// GEMM1': Z^T = B·z^T  → acc lane l holds Z[rbase+(l&15)][nt*16 + 4*(l>>4)+rg]
//   = a per-lane ROW slice: H add / shrink / Hh store are natural f32x4.
// GEMM2': h^T = A^T·Hh^T → B-operand frag needs lane l: Hh[row l&15][8lg+j]
//   obtained from the acc pair by a 4-lane exchange (cndmask + __shfl), no LDS.
__global__ __launch_bounds__(256, 3) void lamp_main(
    const float* __restrict__ zre, const float* __restrict__ zim,
    const float* __restrict__ Hre, const float* __restrict__ Him,
    const unsigned short* __restrict__ pb, const unsigned short* __restrict__ pa,
    const float* __restrict__ sigp, const float* __restrict__ theta,
    float* __restrict__ out, float* __restrict__ bpart)
{
  const int tid = threadIdx.x;
  const int wave = tid >> 6, lane = tid & 63;
  const int l15 = lane & 15, lg = lane >> 4;
  const int rbase = blockIdx.x * 64 + wave * 16;
  const int myrow = rbase + l15;

  const float t0 = theta[0], t1 = theta[1], t2 = theta[2];
  const float sigma = sigp[0];
  const float s2 = (t0 * sigma) * (t0 * sigma);
  const float inv_s2 = 1.0f / s2;
  const float nhalf_inv_s2 = -0.5f * inv_s2;

  // z fragments (B operand of GEMM1'), K padded 48->64; lane: z[myrow][8lg+j]
  i32x4 zr[2], zi[2];
  {
    const float* pr = zre + (size_t)myrow * KK;
    const float* pi = zim + (size_t)myrow * KK;
#pragma unroll
    for (int ks = 0; ks < 2; ++ks) {
      const int k0 = ks*32 + lg*8;
      f32x4 a0 = {0,0,0,0}, a1 = {0,0,0,0}, b0 = {0,0,0,0}, b1 = {0,0,0,0};
      if (k0 < KK) {
        a0 = *(const f32x4*)(pr + k0); a1 = *(const f32x4*)(pr + k0 + 4);
        b0 = *(const f32x4*)(pi + k0); b1 = *(const f32x4*)(pi + k0 + 4);
      }
      zr[ks] = pack8bf(a0, a1);
      zi[ks] = pack8bf(b0, b1);
    }
  }

  const i32x4* pb4 = (const i32x4*)pb;
  const i32x4* pa4 = (const i32x4*)pa;

  // per-lane row-slice bases (f32x4 at col nt*16 + lg*4)
  const float* hrB = Hre + (size_t)myrow * NN + lg*4;
  const float* hiB = Him + (size_t)myrow * NN + lg*4;
  float* oRB = out + OFF_HHRE + (size_t)myrow * NN + lg*4;
  float* oIB = out + OFF_HHIM + (size_t)myrow * NN + lg*4;

  f32x4 ahR[3], ahI[3];
#pragma unroll
  for (int c = 0; c < 3; ++c) { ahR[c] = (f32x4){0,0,0,0}; ahI[c] = (f32x4){0,0,0,0}; }

  float dsr = 0.f, dsi = 0.f;
  const bool hi2 = (lg >= 2);                 // target wants pair-tile 1?
  const int srcA = l15 + ((lane & 16) << 1);  // l15 + 32*(lg&1)
  const int srcB = srcA + 16;

#pragma unroll 1
  for (int t = 0; t < 16; ++t) {
    const int n0 = 2*t, n1 = 2*t + 1;

    // H loads for the pair (consumed after the 16 MFMAs below)
    f32x4 hR0 = *(const f32x4*)(hrB + 32*t);
    f32x4 hR1 = *(const f32x4*)(hrB + 32*t + 16);
    f32x4 hI0 = *(const f32x4*)(hiB + 32*t);
    f32x4 hI1 = *(const f32x4*)(hiB + 32*t + 16);

    i32x4 nzi0 = zi[0] ^ 0x80008000, nzi1 = zi[1] ^ 0x80008000;

    // ---- GEMM1' tile n0 ----
    f32x4 aR0 = (f32x4){0,0,0,0}, aI0 = (f32x4){0,0,0,0};
    {
      i32x4 b0 = pb4[(n0*2 + 0)*64 + lane];
      i32x4 b1 = pb4[(n0*2 + 1)*64 + lane];
      i32x4 c0 = pb4[((32 + n0)*2 + 0)*64 + lane];
      i32x4 c1 = pb4[((32 + n0)*2 + 1)*64 + lane];
      MFMA(aR0, b0, zr[0]); MFMA(aR0, b1, zr[1]);
      MFMA(aR0, c0, nzi0);  MFMA(aR0, c1, nzi1);
      MFMA(aI0, b0, zi[0]); MFMA(aI0, b1, zi[1]);
      MFMA(aI0, c0, zr[0]); MFMA(aI0, c1, zr[1]);
    }
    // ---- GEMM1' tile n1 ----
    f32x4 aR1 = (f32x4){0,0,0,0}, aI1 = (f32x4){0,0,0,0};
    {
      i32x4 b0 = pb4[(n1*2 + 0)*64 + lane];
      i32x4 b1 = pb4[(n1*2 + 1)*64 + lane];
      i32x4 c0 = pb4[((32 + n1)*2 + 0)*64 + lane];
      i32x4 c1 = pb4[((32 + n1)*2 + 1)*64 + lane];
      MFMA(aR1, b0, zr[0]); MFMA(aR1, b1, zr[1]);
      MFMA(aR1, c0, nzi0);  MFMA(aR1, c1, nzi1);
      MFMA(aI1, b0, zi[0]); MFMA(aI1, b1, zi[1]);
      MFMA(aI1, c0, zr[0]); MFMA(aI1, c1, zr[1]);
    }

    // ---- fused elementwise: R = H + Z, shrink, deriv (all f32x4, in-register) ----
    f32x4 re0 = aR0 + hR0, im0 = aI0 + hI0;
    f32x4 re1 = aR1 + hR1, im1 = aI1 + hI1;
    f32x4 hhr0, hhi0, hhr1, hhi1;
#pragma unroll
    for (int c = 0; c < 4; ++c) {
      float x;
      x = re0[c]; { float e = __expf(x*x*nhalf_inv_s2); float te = t2*e;
        hhr0[c] = t1*x + x*te; dsr += t1 + te*(1.f - x*x*inv_s2); }
      x = im0[c]; { float e = __expf(x*x*nhalf_inv_s2); float te = t2*e;
        hhi0[c] = t1*x + x*te; dsi += t1 + te*(1.f - x*x*inv_s2); }
      x = re1[c]; { float e = __expf(x*x*nhalf_inv_s2); float te = t2*e;
        hhr1[c] = t1*x + x*te; dsr += t1 + te*(1.f - x*x*inv_s2); }
      x = im1[c]; { float e = __expf(x*x*nhalf_inv_s2); float te = t2*e;
        hhi1[c] = t1*x + x*te; dsi += t1 + te*(1.f - x*x*inv_s2); }
    }
    __builtin_nontemporal_store(hhr0, (f32x4*)(oRB + 32*t));
    __builtin_nontemporal_store(hhr1, (f32x4*)(oRB + 32*t + 16));
    __builtin_nontemporal_store(hhi0, (f32x4*)(oIB + 32*t));
    __builtin_nontemporal_store(hhi1, (f32x4*)(oIB + 32*t + 16));

    // ---- 4-lane exchange: acc row-slices -> GEMM2' B-operand frags ----
    // target lane (l15,lg) needs Hh[myrow-ish... row l15][32t + 8lg + j], j=0..7
    // source: tile t'=lg>>1 (sel), lane l15 + 32*(lg&1) (+16 for j>=4), reg j&3
    f32x4 selR, selI;
#pragma unroll
    for (int c = 0; c < 4; ++c) {
      selR[c] = hi2 ? hhr1[c] : hhr0[c];
      selI[c] = hi2 ? hhi1[c] : hhi0[c];
    }
    f32x4 w0, w1, v0, v1;
#pragma unroll
    for (int c = 0; c < 4; ++c) {
      w0[c] = __shfl(selR[c], srcA, 64);
      w1[c] = __shfl(selR[c], srcB, 64);
      v0[c] = __shfl(selI[c], srcA, 64);
      v1[c] = __shfl(selI[c], srcB, 64);
    }
    i32x4 hhRf = pack8bf(w0, w1);
    i32x4 hhIf = pack8bf(v0, v1);

    // ---- GEMM2' partial: k-slice t (cols 32t..32t+31) ----
#pragma unroll
    for (int ct = 0; ct < 3; ++ct) {
      i32x4 par = pa4[(t*3 + ct)*64 + lane];
      i32x4 pai = pa4[((16 + t)*3 + ct)*64 + lane];
      i32x4 nai = pai ^ 0x80008000;
      MFMA(ahR[ct], par, hhRf);
      MFMA(ahR[ct], nai, hhIf);
      MFMA(ahI[ct], pai, hhRf);
      MFMA(ahI[ct], par, hhIf);
    }
  }

  // epilogue: h stored as per-lane f32x4 row slices (no transpose needed)
#pragma unroll
  for (int ct = 0; ct < 3; ++ct) {
    *(f32x4*)(out + (size_t)myrow*KK + ct*16 + lg*4) = ahR[ct];
    *(f32x4*)(out + (size_t)(BATCH_*KK) + (size_t)myrow*KK + ct*16 + lg*4) = ahI[ct];
  }

  // per-wave deriv partials (4096 waves)
  float rr = waveRed(dsr), ri = waveRed(dsi);
  if (lane == 0) {
    const int w = blockIdx.x * 4 + wave;
    bpart[2*w]     = rr;
    bpart[2*w + 1] = ri;
  }
}

// ---------------- b reduce (4096 wave-partials) ----------------
__global__ void lamp_bred(const float* __restrict__ bpart, float* __restrict__ bval)
{
  float sr = 0.f, si = 0.f;
  for (int m = threadIdx.x; m < 4096; m += 256) { sr += bpart[2*m]; si += bpart[2*m + 1]; }
  __shared__ float red[8];
  sr = waveRed(sr); si = waveRed(si);
  int wave = threadIdx.x >> 6, lane = threadIdx.x & 63;
  if (lane == 0) { red[wave] = sr; red[4 + wave] = si; }
  __syncthreads();
  if (threadIdx.x == 0) {
    bval[0] = (red[0]+red[1]+red[2]+red[3]) / (float)KK;
    bval[1] = (red[4]+red[5]+red[6]+red[7]) / (float)KK;
  }
}

// ---------------- z_new (in-place over parked h) ----------------
__global__ void lamp_znew(const float* __restrict__ ur, const float* __restrict__ ui,
                          const float* __restrict__ zr, const float* __restrict__ zi,
                          const float* __restrict__ bval, float* __restrict__ out)
{
  const float br = bval[0], bi = bval[1];
  const int n4 = BATCH_*KK/4;
  const f32x4* u4r = (const f32x4*)ur; const f32x4* u4i = (const f32x4*)ui;
  const f32x4* z4r = (const f32x4*)zr; const f32x4* z4i = (const f32x4*)zi;
  f32x4* o4r = (f32x4*)out;
  f32x4* o4i = (f32x4*)(out + BATCH_*KK);
  for (int i = blockIdx.x*blockDim.x + threadIdx.x; i < n4; i += gridDim.x*blockDim.x) {
    f32x4 h = o4r[i];
    o4r[i] = u4r[i] - h + br * z4r[i];
    f32x4 h2 = o4i[i];
    o4i[i] = u4i[i] - h2 + bi * z4i[i];
  }
}

extern "C" void kernel_launch(void* const* d_in, const int* in_sizes, int n_in,
                              void* d_out, int out_size, void* d_ws, size_t ws_size,
                              hipStream_t stream)
{
  const float* ur  = (const float*)d_in[0];
  const float* ui  = (const float*)d_in[1];
  const float* zr  = (const float*)d_in[2];
  const float* zi  = (const float*)d_in[3];
  const float* Hr  = (const float*)d_in[4];
  const float* Hi  = (const float*)d_in[5];
  const float* Bre = (const float*)d_in[6];
  const float* Bim = (const float*)d_in[7];
  const float* Are = (const float*)d_in[8];
  const float* Aim = (const float*)d_in[9];
  const float* th  = (const float*)d_in[10];
  float* out = (float*)d_out;
  char* ws = (char*)d_ws;
  unsigned short* pb  = (unsigned short*)(ws + WS_PB);
  unsigned short* pa  = (unsigned short*)(ws + WS_PA);
  float* sigp  = (float*)(ws + WS_SIGP);
  float* sigv  = (float*)(ws + WS_SIGMA);
  float* bpart = (float*)(ws + WS_BPART);
  float* bval  = (float*)(ws + WS_BVAL);

  hipLaunchKernelGGL(lamp_pack,   dim3(448),  dim3(256), 0, stream, Bre, Bim, Are, Aim, pb, pa);
  hipLaunchKernelGGL(lamp_sig,    dim3(256),  dim3(256), 0, stream, zr, zi, sigp);
  hipLaunchKernelGGL(lamp_sigfin, dim3(1),    dim3(256), 0, stream, sigp, sigv);
  hipLaunchKernelGGL(lamp_main,   dim3(1024), dim3(256), 0, stream,
                     zr, zi, Hr, Hi, pb, pa, sigv, th, out, bpart);
  hipLaunchKernelGGL(lamp_bred,   dim3(1),    dim3(256), 0, stream, bpart, bval);
  hipLaunchKernelGGL(lamp_znew,   dim3(1024), dim3(256), 0, stream, ur, ui, zr, zi, bval, out);
}